// Round 10
// baseline (33.008 us; speedup 1.0000x reference)
//
#include <hip/hip_runtime.h>

typedef float v2f __attribute__((ext_vector_type(2)));

#define BATCH  8
#define NPTS   4096
#define NSLICE 16                 // target-set split per (dir,b)
#define SLICE  (NPTS / NSLICE)    // 256 targets per block
#define TPB1   512                // 8 waves/block, 1 block/CU
#define QPT    8                  // queries per thread (4096 / 512)

// Stage 1: grid = 2 dirs x 8 batches x 16 target-slices = 256 blocks.
// r8 proven skeleton. Round-10 delta: queries packed PAIRWISE into float2
// ext-vectors so the dot-product runs on v_pk_fma_f32 (VOP3P, 2 results per
// issue; target components splat to both halves via op_sel). Reduction stays
// scalar v_min3_f32 on the packed halves. Per 2 targets x 2 queries:
// 6 pk_fma + 2 min3 = 2.0 instr/pair (was 3.5). Worst case the compiler
// scalarizes the fma -> identical instruction stream to r8 (neutral).
// Also: rx is folded into the stored partials (min(m_s)+rx == min(m_s+rx)),
// so stage 2 needs no query loads.
__global__ __launch_bounds__(TPB1, 2) void chamfer_stage1(
    const float* __restrict__ preds,
    const float* __restrict__ gts,
    float* __restrict__ part,     // [16 db][NSLICE][NPTS]
    float* __restrict__ out)
{
    const int blk   = blockIdx.x;
    const int slice = blk % NSLICE;
    const int db    = blk / NSLICE;    // dir*8 + b
    const int dir   = db >> 3;
    const int b     = db & 7;

    if (blk == 0 && threadIdx.x == 0) out[0] = 0.0f;

    const float* Q = dir ? gts   : preds;   // query set
    const float* T = dir ? preds : gts;     // target set

    __shared__ float4 sT[SLICE];            // 4 KiB

    const float* Tb = T + ((size_t)b * NPTS + slice * SLICE) * 3;
    if (threadIdx.x < SLICE) {
        const int j = threadIdx.x;
        const float y0 = Tb[j * 3 + 0];
        const float y1 = Tb[j * 3 + 1];
        const float y2 = Tb[j * 3 + 2];
        sT[j] = make_float4(-2.0f * y0, -2.0f * y1, -2.0f * y2,
                            y0 * y0 + y1 * y1 + y2 * y2);
    }

    // This thread's 8 consecutive queries (24 floats = 6 float4).
    const int q0 = threadIdx.x * QPT;
    const float4* p4 = reinterpret_cast<const float4*>(
        Q + ((size_t)b * NPTS + q0) * 3);
    const float4 v0 = p4[0], v1 = p4[1], v2 = p4[2];
    const float4 v3 = p4[3], v4 = p4[4], v5 = p4[5];

    // Query PAIRS as float2 ext-vectors: pair p = queries (2p, 2p+1).
    const v2f px0 = {v0.x, v0.w}, py0 = {v0.y, v1.x}, pz0 = {v0.z, v1.y};
    const v2f px1 = {v1.z, v2.y}, py1 = {v1.w, v2.z}, pz1 = {v2.x, v2.w};
    const v2f px2 = {v3.x, v3.w}, py2 = {v3.y, v4.x}, pz2 = {v3.z, v4.y};
    const v2f px3 = {v4.z, v5.y}, py3 = {v4.w, v5.z}, pz3 = {v5.x, v5.w};

    // ||q||^2 per query (folded into the stored partial mins).
    const float rx0 = fmaf(v0.x, v0.x, fmaf(v0.y, v0.y, v0.z * v0.z));
    const float rx1 = fmaf(v0.w, v0.w, fmaf(v1.x, v1.x, v1.y * v1.y));
    const float rx2 = fmaf(v1.z, v1.z, fmaf(v1.w, v1.w, v2.x * v2.x));
    const float rx3 = fmaf(v2.y, v2.y, fmaf(v2.z, v2.z, v2.w * v2.w));
    const float rx4 = fmaf(v3.x, v3.x, fmaf(v3.y, v3.y, v3.z * v3.z));
    const float rx5 = fmaf(v3.w, v3.w, fmaf(v4.x, v4.x, v4.y * v4.y));
    const float rx6 = fmaf(v4.z, v4.z, fmaf(v4.w, v4.w, v5.x * v5.x));
    const float rx7 = fmaf(v5.y, v5.y, fmaf(v5.z, v5.z, v5.w * v5.w));

    __syncthreads();

    float m0 = 3.4e38f, m1 = 3.4e38f, m2 = 3.4e38f, m3 = 3.4e38f;
    float m4 = 3.4e38f, m5 = 3.4e38f, m6 = 3.4e38f, m7 = 3.4e38f;

    // e = ||y||^2 - 2*dot(q,y); two targets (ya,yb) x query-pair p per step:
    // 6 v_pk_fma_f32 + 2 v_min3_f32.
    #define DO_P(p, ka, kb) { \
        const v2f eA = __builtin_elementwise_fma(px##p, yax, \
                        __builtin_elementwise_fma(py##p, yay, \
                         __builtin_elementwise_fma(pz##p, yaz, yaw))); \
        const v2f eB = __builtin_elementwise_fma(px##p, ybx, \
                        __builtin_elementwise_fma(py##p, yby, \
                         __builtin_elementwise_fma(pz##p, ybz, ybw))); \
        m##ka = fminf(m##ka, fminf(eA.x, eB.x)); \
        m##kb = fminf(m##kb, fminf(eA.y, eB.y)); }

    #pragma unroll 4
    for (int j = 0; j < SLICE; j += 2) {
        const float4 ya = sT[j];
        const float4 yb = sT[j + 1];
        const v2f yax = {ya.x, ya.x}, yay = {ya.y, ya.y};
        const v2f yaz = {ya.z, ya.z}, yaw = {ya.w, ya.w};
        const v2f ybx = {yb.x, yb.x}, yby = {yb.y, yb.y};
        const v2f ybz = {yb.z, yb.z}, ybw = {yb.w, yb.w};
        DO_P(0, 0, 1) DO_P(1, 2, 3) DO_P(2, 4, 5) DO_P(3, 6, 7)
    }
    #undef DO_P

    // Coalesced 32 B/thread store with rx folded in:
    // part[db][slice][q0..q0+7] = partial_min + ||q||^2
    float4* b4 = reinterpret_cast<float4*>(
        part + ((size_t)db * NSLICE + slice) * NPTS + q0);
    b4[0] = make_float4(m0 + rx0, m1 + rx1, m2 + rx2, m3 + rx3);
    b4[1] = make_float4(m4 + rx4, m5 + rx5, m6 + rx6, m7 + rx7);
}

// Stage 2: one thread per query; min over the 16 slice-partials (rx already
// folded in), block-reduce, one atomicAdd per block.
#define TPB2 256
__global__ __launch_bounds__(TPB2) void chamfer_stage2(
    const float* __restrict__ part,
    float* __restrict__ out)
{
    const int g  = blockIdx.x * TPB2 + threadIdx.x;   // [0, 2*8*4096)
    const int db = g >> 12;
    const int q  = g & (NPTS - 1);

    const float* pp = part + (size_t)db * NSLICE * NPTS + q;
    float m = 3.4e38f;
    #pragma unroll
    for (int s = 0; s < NSLICE; ++s)
        m = fminf(m, pp[(size_t)s * NPTS]);

    float s = m;

    #pragma unroll
    for (int off = 32; off > 0; off >>= 1)
        s += __shfl_down(s, off, 64);

    __shared__ float red[TPB2 / 64];
    const int lane = threadIdx.x & 63;
    const int wid  = threadIdx.x >> 6;
    if (lane == 0) red[wid] = s;
    __syncthreads();
    if (threadIdx.x == 0) {
        float t = 0.0f;
        #pragma unroll
        for (int w = 0; w < TPB2 / 64; ++w) t += red[w];
        atomicAdd(out, t);
    }
}

extern "C" void kernel_launch(void* const* d_in, const int* in_sizes, int n_in,
                              void* d_out, int out_size, void* d_ws, size_t ws_size,
                              hipStream_t stream) {
    const float* preds = (const float*)d_in[0];
    const float* gts   = (const float*)d_in[1];
    float* out  = (float*)d_out;
    float* part = (float*)d_ws;   // 16 db x 16 slices x 4096 floats = 4 MiB

    // Only 2 dispatches: stage1 zeroes `out` itself; `part` is fully
    // written by stage 1 before stage 2 reads it — no memsets needed.
    chamfer_stage1<<<dim3(2 * BATCH * NSLICE), TPB1, 0, stream>>>(preds, gts, part, out);
    chamfer_stage2<<<dim3(2 * BATCH * NPTS / TPB2), TPB2, 0, stream>>>(part, out);
}